// Round 8
// baseline (884.645 us; speedup 1.0000x reference)
//
#include <hip/hip_runtime.h>
#include <hip/hip_fp16.h>
#include <cmath>

// INGP hashgrid encode — one-pass v2 (spill-proof lockstep).
//   1024 blocks, 4/CU co-resident (launch_bounds(256,4)), each owns 512
//   consecutive points and sweeps levels 15..0 in lockstep: all XCDs gather
//   from the SAME 4MiB table at any instant -> pins in every L2, perfectly
//   balanced ~5.7M L2-requests/XCD (R6 worst XCD: 6.3M).
//   R7 post-mortem: acc[2][16][2] fp32 spilled to scratch (VGPR capped 64,
//   WRITE_SIZE 1.14GB) -> acc now packed half2 (32 VGPRs), fp32 math per
//   level, one rounding at pack (+5e-8 err; budget 1.97e-6, have 4.8e-7).
//   Fine->coarse order: uniform heavy levels run while blocks are synced;
//   drift lands in L1-resident coarse levels where it's harmless.
//   Epilogue: half2 LDS shuffle -> coalesced 16B full-row stores. No ws, no
//   transpose kernel (~27us), no cross-XCD output lines (R5 lesson).

constexpr int LVLS = 16;
constexpr unsigned TBL = 1u << 19;
constexpr unsigned TMASK = TBL - 1u;
constexpr unsigned P1 = 2654435761u;
constexpr unsigned P2 = 805459861u;

typedef float vf4 __attribute__((ext_vector_type(4)));

struct ResArr { float r[LVLS]; };

__global__ __launch_bounds__(256, 4) void ingp_onepass2(
    const float* __restrict__ pts,
    const float* __restrict__ tables,
    float* __restrict__ out,      // [N][LVLS*2] floats
    ResArr ra, int npts)
{
    int t = threadIdx.x;
    int base = blockIdx.x * 512;

    float X[2], Y[2], Z[2];
    int pidx[2] = { base + t, base + t + 256 };
    #pragma unroll
    for (int s = 0; s < 2; ++s) {
        int pp = pidx[s] < npts ? pidx[s] : 0;
        float px = __builtin_nontemporal_load(pts + pp * 3 + 0);
        float py = __builtin_nontemporal_load(pts + pp * 3 + 1);
        float pz = __builtin_nontemporal_load(pts + pp * 3 + 2);
        X[s] = (px + 1.0f) * 0.5f;
        Y[s] = (py + 1.0f) * 0.5f;
        Z[s] = (pz + 1.0f) * 0.5f;
    }

    __half2 acc[2][LVLS];   // packed accumulator: 32 VGPRs total (no spill)

    #pragma unroll
    for (int li = 0; li < LVLS; ++li) {
        const int l = LVLS - 1 - li;           // fine -> coarse
        float r = ra.r[l];
        const float2* __restrict__ tab = (const float2*)tables + (size_t)l * TBL;

        #pragma unroll
        for (int s = 0; s < 2; ++s) {
            float posx = X[s] * r, posy = Y[s] * r, posz = Z[s] * r;
            float fx = floorf(posx), fy = floorf(posy), fz = floorf(posz);
            float wx = posx - fx, wy = posy - fy, wz = posz - fz;
            unsigned ix = (unsigned)fx, iy = (unsigned)fy, iz = (unsigned)fz;
            unsigned hx0 = ix,      hx1 = ix + 1u;
            unsigned hy0 = iy * P1, hy1 = hy0 + P1;
            unsigned hz0 = iz * P2, hz1 = hz0 + P2;

            unsigned hyz[4];
            hyz[0] = hy0 ^ hz0;
            hyz[1] = hy0 ^ hz1;
            hyz[2] = hy1 ^ hz0;
            hyz[3] = hy1 ^ hz1;

            // v[i*4+yz] = corner (i,j,k); x-pairs share an aligned float4
            // when ix is even (R6-validated: 8 -> 6 avg line-requests).
            float2 v[8];
            if ((ix & 1u) == 0u) {
                #pragma unroll
                for (int yz = 0; yz < 4; ++yz) {
                    unsigned b0 = (hx0 ^ hyz[yz]) & TMASK;
                    const vf4* lp = (const vf4*)(tab + (b0 & ~1u));
                    vf4 qd = *lp;
                    float2 lo = make_float2(qd.x, qd.y);
                    float2 hi = make_float2(qd.z, qd.w);
                    bool odd = (b0 & 1u) != 0u;
                    v[yz]     = odd ? hi : lo;
                    v[4 + yz] = odd ? lo : hi;
                }
            } else {
                #pragma unroll
                for (int yz = 0; yz < 4; ++yz) {
                    unsigned b0 = (hx0 ^ hyz[yz]) & TMASK;
                    unsigned b1 = (hx1 ^ hyz[yz]) & TMASK;
                    v[yz]     = tab[b0];
                    v[4 + yz] = tab[b1];
                }
            }

            float ox = 1.0f - wx, oy = 1.0f - wy, oz = 1.0f - wz;
            float w[8];
            w[0] = (ox * oy) * oz;
            w[1] = (ox * oy) * wz;
            w[2] = (ox * wy) * oz;
            w[3] = (ox * wy) * wz;
            w[4] = (wx * oy) * oz;
            w[5] = (wx * oy) * wz;
            w[6] = (wx * wy) * oz;
            w[7] = (wx * wy) * wz;

            float f0 = w[0] * v[0].x;
            float f1 = w[0] * v[0].y;
            #pragma unroll
            for (int c = 1; c < 8; ++c) {
                f0 += w[c] * v[c].x;
                f1 += w[c] * v[c].y;
            }
            acc[s][l] = __floats2half2_rn(f0, f1);   // fp32 math, one rounding
        }
        __syncthreads();   // drift limiter: keep the block's waves on one table
    }

    // Epilogue: half2 LDS shuffle -> coalesced 16B stores of complete rows.
    __shared__ __half2 lds[256][LVLS + 1];   // stride 17: conflict-light
    int j = t & 7;     // which float4 of the 128B output row
    int pr = t >> 3;   // point-in-tile, advances by 32

    #pragma unroll
    for (int h = 0; h < 2; ++h) {
        __syncthreads();
        #pragma unroll
        for (int l = 0; l < LVLS; ++l)
            lds[t][l] = acc[h][l];
        __syncthreads();

        #pragma unroll
        for (int it = 0; it < 8; ++it) {
            int pt = pr + it * 32;
            int gp = base + h * 256 + pt;
            if (gp < npts) {
                float2 ua = __half22float2(lds[pt][2 * j]);
                float2 ub = __half22float2(lds[pt][2 * j + 1]);
                vf4 o; o.x = ua.x; o.y = ua.y; o.z = ub.x; o.w = ub.y;
                __builtin_nontemporal_store(o, (vf4*)(out + (size_t)gp * 32 + j * 4));
            }
        }
    }
}

extern "C" void kernel_launch(void* const* d_in, const int* in_sizes, int n_in,
                              void* d_out, int out_size, void* d_ws, size_t ws_size,
                              hipStream_t stream) {
    const float* pts    = (const float*)d_in[0];
    const float* tables = (const float*)d_in[1];
    int npts = in_sizes[0] / 3;

    // numpy-bitwise RES: GROWTH = exp((log(2048)-log(16))/15); floor(16*G**l)
    ResArr ra;
    double growth = exp((log(2048.0) - log(16.0)) / 15.0);
    for (int l = 0; l < LVLS; ++l)
        ra.r[l] = (float)floor(16.0 * pow(growth, (double)l));

    int grid = (npts + 511) / 512;
    hipLaunchKernelGGL(ingp_onepass2, dim3(grid), dim3(256), 0, stream,
                       pts, tables, (float*)d_out, ra, npts);
}